// Round 2
// baseline (1331.116 us; speedup 1.0000x reference)
//
#include <hip/hip_runtime.h>

#define B_  8
#define L_  2048
#define C_  512
#define R_  256
#define H_  8
#define DK_ 64
#define HD_ 512
#define MASK_NEG (-32767.0f)

// ---------------- generic tiled fp32 GEMM ----------------
// C[M,N] = scale * op(A) @ op(B); TA: A is [K,M] row-major; TB: B is [N,K] row-major.
// Batched via blockIdx.z: zb=z/divz, zh=z%divz; base += zb*sb + zh*sh per operand.
// EPI==0: store C. EPI==1: no store; atomicAdd sum of (c^2) over global row!=col into lossAcc.
template<bool TA, bool TB, int EPI>
__global__ __launch_bounds__(256) void gemm_f32(
    const float* __restrict__ A, const float* __restrict__ Bm, float* __restrict__ Cm,
    int M, int N, int K, int lda, int ldb, int ldc,
    int divz, long long asb, long long ash, long long bsb, long long bsh,
    long long csb, long long csh, float scale, float* __restrict__ lossAcc)
{
    __shared__ float As[16][65];
    __shared__ float Bs[16][65];
    __shared__ float red[4];

    const int z  = blockIdx.z;
    const int zb = z / divz, zh = z - zb * divz;
    A  += zb * asb + zh * ash;
    Bm += zb * bsb + zh * bsh;
    if (EPI == 0) Cm += zb * csb + zh * csh;

    const int m0 = blockIdx.y * 64, n0 = blockIdx.x * 64;
    const int tid = threadIdx.x;
    const int tx = tid & 15, ty = tid >> 4;

    float acc[4][4] = {};

    for (int k0 = 0; k0 < K; k0 += 16) {
        if (!TA) {  // A is M x K
            int r  = tid >> 2;
            int c4 = (tid & 3) << 2;
            float4 v = *(const float4*)(A + (long long)(m0 + r) * lda + (k0 + c4));
            As[c4+0][r] = v.x; As[c4+1][r] = v.y; As[c4+2][r] = v.z; As[c4+3][r] = v.w;
        } else {    // A is K x M
            int rr = tid >> 4;
            int c4 = (tid & 15) << 2;
            float4 v = *(const float4*)(A + (long long)(k0 + rr) * lda + (m0 + c4));
            As[rr][c4+0] = v.x; As[rr][c4+1] = v.y; As[rr][c4+2] = v.z; As[rr][c4+3] = v.w;
        }
        if (!TB) {  // B is K x N
            int rr = tid >> 4;
            int c4 = (tid & 15) << 2;
            float4 v = *(const float4*)(Bm + (long long)(k0 + rr) * ldb + (n0 + c4));
            Bs[rr][c4+0] = v.x; Bs[rr][c4+1] = v.y; Bs[rr][c4+2] = v.z; Bs[rr][c4+3] = v.w;
        } else {    // B is N x K
            int r  = tid >> 2;
            int c4 = (tid & 3) << 2;
            float4 v = *(const float4*)(Bm + (long long)(n0 + r) * ldb + (k0 + c4));
            Bs[c4+0][r] = v.x; Bs[c4+1][r] = v.y; Bs[c4+2][r] = v.z; Bs[c4+3][r] = v.w;
        }
        __syncthreads();
        #pragma unroll
        for (int kk = 0; kk < 16; ++kk) {
            float a[4], b[4];
            #pragma unroll
            for (int i = 0; i < 4; ++i) a[i] = As[kk][ty * 4 + i];
            #pragma unroll
            for (int j = 0; j < 4; ++j) b[j] = Bs[kk][tx * 4 + j];
            #pragma unroll
            for (int i = 0; i < 4; ++i)
                #pragma unroll
                for (int j = 0; j < 4; ++j)
                    acc[i][j] += a[i] * b[j];
        }
        __syncthreads();
    }

    if (EPI == 0) {
        #pragma unroll
        for (int i = 0; i < 4; ++i) {
            float4 v = make_float4(acc[i][0] * scale, acc[i][1] * scale,
                                   acc[i][2] * scale, acc[i][3] * scale);
            *(float4*)(Cm + (long long)(m0 + ty * 4 + i) * ldc + (n0 + tx * 4)) = v;
        }
    } else {
        float s = 0.0f;
        #pragma unroll
        for (int i = 0; i < 4; ++i)
            #pragma unroll
            for (int j = 0; j < 4; ++j) {
                int rm = m0 + ty * 4 + i, rn = n0 + tx * 4 + j;
                if (rm != rn) { float c = acc[i][j] * scale; s += c * c; }
            }
        #pragma unroll
        for (int off = 32; off; off >>= 1) s += __shfl_down(s, off, 64);
        int lane = tid & 63, wid = tid >> 6;
        if (lane == 0) red[wid] = s;
        __syncthreads();
        if (tid == 0) atomicAdd(lossAcc, red[0] + red[1] + red[2] + red[3]);
    }
}

// ---------------- softmax kernels ----------------
__device__ inline float waveMax(float v) {
    #pragma unroll
    for (int o = 32; o; o >>= 1) v = fmaxf(v, __shfl_xor(v, o, 64));
    return v;
}
__device__ inline float waveSum(float v) {
    #pragma unroll
    for (int o = 32; o; o >>= 1) v += __shfl_xor(v, o, 64);
    return v;
}

// pAlpha[b,r,l] = softmax over l of masked pScore[b,l,r]
// mask is int32 (bool input promoted to int by harness); row 0 of [L,L] per batch.
__global__ __launch_bounds__(256) void softmax_L(
    const float* __restrict__ pScore, const int* __restrict__ mask,
    float* __restrict__ pAlpha)
{
    __shared__ float sm[4], ss[4];
    int z = blockIdx.x;          // b*R + r
    int b = z >> 8, r = z & 255;
    const float* ps = pScore + (long long)b * L_ * R_ + r;
    const int* mk = mask + (long long)b * L_ * L_;  // row 0 of [L,L]
    float vals[8];
    float mx = -3.4e38f;
    #pragma unroll
    for (int i = 0; i < 8; ++i) {
        int l = threadIdx.x + i * 256;
        float v = ps[(long long)l * R_];
        if (mk[l] == 0) v = MASK_NEG;
        vals[i] = v; mx = fmaxf(mx, v);
    }
    int lane = threadIdx.x & 63, wid = threadIdx.x >> 6;
    mx = waveMax(mx);
    if (lane == 0) sm[wid] = mx;
    __syncthreads();
    mx = fmaxf(fmaxf(sm[0], sm[1]), fmaxf(sm[2], sm[3]));
    float sum = 0.0f;
    #pragma unroll
    for (int i = 0; i < 8; ++i) { float e = __expf(vals[i] - mx); vals[i] = e; sum += e; }
    sum = waveSum(sum);
    if (lane == 0) ss[wid] = sum;
    __syncthreads();
    sum = ss[0] + ss[1] + ss[2] + ss[3];
    float inv = 1.0f / sum;
    float* out = pAlpha + ((long long)b * R_ + r) * L_;
    #pragma unroll
    for (int i = 0; i < 8; ++i) out[threadIdx.x + i * 256] = vals[i] * inv;
}

// pAlpha_[b,l,r] = softmax over r of masked pScore[b,l,r]
__global__ __launch_bounds__(256) void softmax_R(
    const float* __restrict__ pScore, const int* __restrict__ mask,
    float* __restrict__ pAlpha_)
{
    __shared__ float sm[4], ss[4];
    long long z = blockIdx.x;    // b*L + l
    int b = (int)(z >> 11), l = (int)(z & 2047);
    bool pad = (mask[(long long)b * L_ * L_ + l] == 0);
    float v = pScore[z * R_ + threadIdx.x];
    if (pad) v = MASK_NEG;
    int lane = threadIdx.x & 63, wid = threadIdx.x >> 6;
    float mx = waveMax(v);
    if (lane == 0) sm[wid] = mx;
    __syncthreads();
    mx = fmaxf(fmaxf(sm[0], sm[1]), fmaxf(sm[2], sm[3]));
    float e = __expf(v - mx);
    float sum = waveSum(e);
    if (lane == 0) ss[wid] = sum;
    __syncthreads();
    sum = ss[0] + ss[1] + ss[2] + ss[3];
    pAlpha_[z * R_ + threadIdx.x] = e / sum;
}

// alpha = softmax(scores, -1) with off-diagonal sum accumulated into loss2
__global__ __launch_bounds__(256) void softmax_alpha(
    const float* __restrict__ scores, float* __restrict__ alpha, float* __restrict__ loss2)
{
    __shared__ float sm[4], ss[4], so[4];
    long long row = blockIdx.x;  // over B*H*R
    int r = (int)(row & 255);
    float v = scores[row * 256 + threadIdx.x];
    int lane = threadIdx.x & 63, wid = threadIdx.x >> 6;
    float mx = waveMax(v);
    if (lane == 0) sm[wid] = mx;
    __syncthreads();
    mx = fmaxf(fmaxf(sm[0], sm[1]), fmaxf(sm[2], sm[3]));
    float e = __expf(v - mx);
    float sum = waveSum(e);
    if (lane == 0) ss[wid] = sum;
    __syncthreads();
    sum = ss[0] + ss[1] + ss[2] + ss[3];
    float a = e / sum;
    alpha[row * 256 + threadIdx.x] = a;
    float off = (threadIdx.x == r) ? 0.0f : a;
    off = waveSum(off);
    if (lane == 0) so[wid] = off;
    __syncthreads();
    if (threadIdx.x == 0) atomicAdd(loss2, so[0] + so[1] + so[2] + so[3]);
}

__global__ void finalize_loss(const float* __restrict__ addLossIn,
                              const float* __restrict__ lossAcc, float* __restrict__ out)
{
    out[0] = addLossIn[0]
           + lossAcc[0] * (1.0f / ((float)B_ * R_ * R_))
           + lossAcc[1] * (1.0f / ((float)B_ * H_ * R_ * R_))
           + lossAcc[2] * (1.0f / ((float)B_ * R_ * R_));
}

// ---------------- launch ----------------
extern "C" void kernel_launch(void* const* d_in, const int* in_sizes, int n_in,
                              void* d_out, int out_size, void* d_ws, size_t ws_size,
                              hipStream_t stream)
{
    const float* qx = (const float*)d_in[0];
    const float* kx = (const float*)d_in[1];
    const float* vx = (const float*)d_in[2];
    const float* addLossIn = (const float*)d_in[3];
    const int* mask = (const int*)d_in[4];
    const float* Wp = (const float*)d_in[5];
    const float* WQ = (const float*)d_in[6];
    const float* WK = (const float*)d_in[7];
    const float* WV = (const float*)d_in[8];
    const float* WO = (const float*)d_in[9];

    float* zOut      = (float*)d_out;                       // [B,L,C]
    float* scoresOut = zOut + (long long)B_ * L_ * C_;      // [B,H,R,R]
    float* lossOut   = scoresOut + (long long)B_ * H_ * R_ * R_;  // [1]

    float* w = (float*)d_ws;
    const long long SZ_BLR = (long long)B_ * L_ * R_;       // 4M
    const long long SZ_BRC = (long long)B_ * R_ * C_;       // 1M
    float* pScore  = w;                    // 4M  (reused by alpha later)
    float* pAlpha  = w + SZ_BLR;           // 4M
    float* pAlpha_ = w + 2 * SZ_BLR;       // 4M
    float* qr = w + 3 * SZ_BLR;            // 1M
    float* kr = qr + SZ_BRC;
    float* vr = kr + SZ_BRC;
    float* qp = vr + SZ_BRC;
    float* kp = qp + SZ_BRC;
    float* vp = kp + SZ_BRC;
    float* z1 = vp + SZ_BRC;               // [B,R,HD]
    float* alpha = pScore;                 // reuse: pScore dead after softmaxes
    float* z2 = qr;                        // reuse: qr dead after projection
    float* loss = z1 + SZ_BRC;             // 3 floats

    hipMemsetAsync(loss, 0, 3 * sizeof(float), stream);

    // 1) pScore = vx @ Wp^T   [B*L, R]
    gemm_f32<false, true, 0><<<dim3(R_/64, (B_*L_)/64, 1), 256, 0, stream>>>(
        vx, Wp, pScore, B_*L_, R_, C_, C_, C_, R_,
        1, 0, 0, 0, 0, 0, 0, 1.0f, nullptr);

    // 2) softmaxes
    softmax_L<<<B_*R_, 256, 0, stream>>>(pScore, mask, pAlpha);
    softmax_R<<<B_*L_, 256, 0, stream>>>(pScore, mask, pAlpha_);

    // 3) loss1: sum offdiag (pAlpha @ pAlpha^T)^2
    gemm_f32<false, true, 1><<<dim3(4, 4, B_), 256, 0, stream>>>(
        pAlpha, pAlpha, nullptr, R_, R_, L_, L_, L_, 0,
        1, (long long)R_*L_, 0, (long long)R_*L_, 0, 0, 0, 1.0f, loss + 0);

    // 4) loss3: sum offdiag (pAlpha_^T @ pAlpha_)^2
    gemm_f32<true, false, 1><<<dim3(4, 4, B_), 256, 0, stream>>>(
        pAlpha_, pAlpha_, nullptr, R_, R_, L_, R_, R_, 0,
        1, (long long)L_*R_, 0, (long long)L_*R_, 0, 0, 0, 1.0f, loss + 2);

    // 5) qr/kr/vr = pAlpha @ {qx,kx,vx}   [B][R,C]
    gemm_f32<false, false, 0><<<dim3(C_/64, R_/64, B_), 256, 0, stream>>>(
        pAlpha, qx, qr, R_, C_, L_, L_, C_, C_,
        1, (long long)R_*L_, 0, (long long)L_*C_, 0, (long long)R_*C_, 0, 1.0f, nullptr);
    gemm_f32<false, false, 0><<<dim3(C_/64, R_/64, B_), 256, 0, stream>>>(
        pAlpha, kx, kr, R_, C_, L_, L_, C_, C_,
        1, (long long)R_*L_, 0, (long long)L_*C_, 0, (long long)R_*C_, 0, 1.0f, nullptr);
    gemm_f32<false, false, 0><<<dim3(C_/64, R_/64, B_), 256, 0, stream>>>(
        pAlpha, vx, vr, R_, C_, L_, L_, C_, C_,
        1, (long long)R_*L_, 0, (long long)L_*C_, 0, (long long)R_*C_, 0, 1.0f, nullptr);

    // 6) projections: [B*R, HD] = xr @ W^T
    gemm_f32<false, true, 0><<<dim3(HD_/64, (B_*R_)/64, 1), 256, 0, stream>>>(
        qr, WQ, qp, B_*R_, HD_, C_, C_, C_, HD_,
        1, 0, 0, 0, 0, 0, 0, 1.0f, nullptr);
    gemm_f32<false, true, 0><<<dim3(HD_/64, (B_*R_)/64, 1), 256, 0, stream>>>(
        kr, WK, kp, B_*R_, HD_, C_, C_, C_, HD_,
        1, 0, 0, 0, 0, 0, 0, 1.0f, nullptr);
    gemm_f32<false, true, 0><<<dim3(HD_/64, (B_*R_)/64, 1), 256, 0, stream>>>(
        vr, WV, vp, B_*R_, HD_, C_, C_, C_, HD_,
        1, 0, 0, 0, 0, 0, 0, 1.0f, nullptr);

    // 7) scores[b,h] = qp[b,:,h*64:+64] @ kp[b,:,h*64:+64]^T / 8
    gemm_f32<false, true, 0><<<dim3(4, 4, B_*H_), 256, 0, stream>>>(
        qp, kp, scoresOut, R_, R_, DK_, HD_, HD_, R_,
        H_, (long long)R_*HD_, 64, (long long)R_*HD_, 64,
        (long long)H_*R_*R_, (long long)R_*R_, 0.125f, nullptr);

    // 8) alpha = softmax(scores) + loss2
    softmax_alpha<<<B_*H_*R_, 256, 0, stream>>>(scoresOut, alpha, loss + 1);

    // 9) z1[b,:,h*64:+64] = alpha[b,h] @ vp[b,:,h*64:+64]
    gemm_f32<false, false, 0><<<dim3(1, 4, B_*H_), 256, 0, stream>>>(
        alpha, vp, z1, R_, DK_, R_, R_, HD_, HD_,
        H_, (long long)H_*R_*R_, (long long)R_*R_,
        (long long)R_*HD_, 64, (long long)R_*HD_, 64, 1.0f, nullptr);

    // 10) z2 = z1 @ WO^T   [B*R, C]
    gemm_f32<false, true, 0><<<dim3(C_/64, (B_*R_)/64, 1), 256, 0, stream>>>(
        z1, WO, z2, B_*R_, C_, HD_, HD_, HD_, C_,
        1, 0, 0, 0, 0, 0, 0, 1.0f, nullptr);

    // 11) z = pAlpha_ @ z2   [B][L,C]
    gemm_f32<false, false, 0><<<dim3(C_/64, L_/64, B_), 256, 0, stream>>>(
        pAlpha_, z2, zOut, L_, C_, R_, R_, C_, C_,
        1, (long long)L_*R_, 0, (long long)R_*C_, 0, (long long)L_*C_, 0, 1.0f, nullptr);

    // 12) addLoss
    finalize_loss<<<1, 1, 0, stream>>>(addLossIn, loss, lossOut);
}

// Round 4
// 997.128 us; speedup vs baseline: 1.3350x; 1.3350x over previous
//
#include <hip/hip_runtime.h>

#define B_  8
#define L_  2048
#define C_  512
#define R_  256
#define H_  8
#define DK_ 64
#define HD_ 512
#define MASK_NEG (-32767.0f)

typedef __attribute__((ext_vector_type(8))) short short8;
typedef __attribute__((ext_vector_type(4))) float f32x4;

__device__ inline unsigned short bf16_rne(float x) {
    unsigned u = __float_as_uint(x);
    return (unsigned short)((u + 0x7FFFu + ((u >> 16) & 1u)) >> 16);
}
// returns hi bf16 in low 16 bits, lo bf16 in high 16 bits
__device__ inline unsigned cvt_hl(float x) {
    unsigned short hh = bf16_rne(x);
    float hf = __uint_as_float(((unsigned)hh) << 16);
    unsigned short ll = bf16_rne(x - hf);
    return (unsigned)hh | ((unsigned)ll << 16);
}

// ---------------- MFMA split-bf16 GEMM ----------------
// C[M,N] = scale * A @ B computed as Ah@Bh + Ah@Bl + Al@Bh (hi/lo bf16 split of fp32).
// AKM=false: A global is [M][K] row-major. AKM=true: A is [K][M].
// BKM=false: B global is [N][K] row-major (op(B)=B^T). BKM=true: B is [K][N].
// Tile: BM=64 x BN x BK=32. 4 waves, each 32 x BN/2.
// Batch: z -> zb=z/divz, zh=z%divz. TRIPLE: zb selects pointer triple, else *sb strides.
// EPI 0: store C*scale. EPI 1: atomicAdd sum of offdiag(C)^2 into lossAcc (no store).
template<int BN, bool AKM, bool BKM, int EPI, bool TRIPLE>
__global__ __launch_bounds__(256) void gemm_mx(
    const float* __restrict__ A0, const float* __restrict__ A1, const float* __restrict__ A2,
    const float* __restrict__ B0, const float* __restrict__ B1, const float* __restrict__ B2,
    float* __restrict__ C0, float* __restrict__ C1, float* __restrict__ C2,
    int K, int lda, int ldb, int ldc, int divz,
    long long asb, long long ash, long long bsb, long long bsh,
    long long csb, long long csh, float scale, float* __restrict__ lossAcc)
{
    constexpr int NF = BN / 32;
    __shared__ short Ah[64][40], Al[64][40];
    __shared__ short Bh[BN][40], Bl[BN][40];
    __shared__ float red[4];

    const int z  = blockIdx.z;
    const int zb = z / divz, zh = z - zb * divz;
    const float* A  = TRIPLE ? (zb == 0 ? A0 : zb == 1 ? A1 : A2) : A0;
    const float* Bg = TRIPLE ? (zb == 0 ? B0 : zb == 1 ? B1 : B2) : B0;
    float*       Cg = TRIPLE ? (zb == 0 ? C0 : zb == 1 ? C1 : C2) : C0;
    A  += (TRIPLE ? 0 : zb * asb) + zh * ash;
    Bg += (TRIPLE ? 0 : zb * bsb) + zh * bsh;
    Cg += (TRIPLE ? 0 : zb * csb) + zh * csh;

    const int m0 = blockIdx.y * 64, n0 = blockIdx.x * BN;
    const int tid = threadIdx.x;
    const int lane = tid & 63, w = tid >> 6;
    const int wrow = (w >> 1) * 32, wcol = (w & 1) * (BN / 2);
    const int l15 = lane & 15, lg = lane >> 4;

    f32x4 zero = {0.f, 0.f, 0.f, 0.f};
    f32x4 acc[2][NF];
    #pragma unroll
    for (int mf = 0; mf < 2; ++mf)
        #pragma unroll
        for (int nf = 0; nf < NF; ++nf) acc[mf][nf] = zero;

    for (int k0 = 0; k0 < K; k0 += 32) {
        // ---- stage A: 64 x 32 fp32 -> hi/lo bf16 LDS [m][k] ----
        if (!AKM) {
            #pragma unroll
            for (int i = 0; i < 2; ++i) {
                int idx = tid + i * 256;
                int row = idx >> 3, kc = (idx & 7) << 2;
                float4 v = *(const float4*)(A + (long long)(m0 + row) * lda + (k0 + kc));
                unsigned p0 = cvt_hl(v.x), p1 = cvt_hl(v.y), p2 = cvt_hl(v.z), p3 = cvt_hl(v.w);
                Ah[row][kc+0] = (short)(p0 & 0xFFFF); Al[row][kc+0] = (short)(p0 >> 16);
                Ah[row][kc+1] = (short)(p1 & 0xFFFF); Al[row][kc+1] = (short)(p1 >> 16);
                Ah[row][kc+2] = (short)(p2 & 0xFFFF); Al[row][kc+2] = (short)(p2 >> 16);
                Ah[row][kc+3] = (short)(p3 & 0xFFFF); Al[row][kc+3] = (short)(p3 >> 16);
            }
        } else {
            #pragma unroll
            for (int i = 0; i < 2; ++i) {
                int idx = tid + i * 256;
                int kr = idx >> 4, mc = (idx & 15) << 2;
                float4 v = *(const float4*)(A + (long long)(k0 + kr) * lda + (m0 + mc));
                float vv[4] = {v.x, v.y, v.z, v.w};
                #pragma unroll
                for (int j = 0; j < 4; ++j) {
                    unsigned p = cvt_hl(vv[j]);
                    Ah[mc + j][kr] = (short)(p & 0xFFFF);
                    Al[mc + j][kr] = (short)(p >> 16);
                }
            }
        }
        // ---- stage B: BN x 32 -> hi/lo bf16 LDS [n][k] ----
        if (!BKM) {
            #pragma unroll
            for (int i = 0; i < BN / 32; ++i) {
                int idx = tid + i * 256;
                int row = idx >> 3, kc = (idx & 7) << 2;
                float4 v = *(const float4*)(Bg + (long long)(n0 + row) * ldb + (k0 + kc));
                unsigned p0 = cvt_hl(v.x), p1 = cvt_hl(v.y), p2 = cvt_hl(v.z), p3 = cvt_hl(v.w);
                Bh[row][kc+0] = (short)(p0 & 0xFFFF); Bl[row][kc+0] = (short)(p0 >> 16);
                Bh[row][kc+1] = (short)(p1 & 0xFFFF); Bl[row][kc+1] = (short)(p1 >> 16);
                Bh[row][kc+2] = (short)(p2 & 0xFFFF); Bl[row][kc+2] = (short)(p2 >> 16);
                Bh[row][kc+3] = (short)(p3 & 0xFFFF); Bl[row][kc+3] = (short)(p3 >> 16);
            }
        } else {
            #pragma unroll
            for (int i = 0; i < BN / 32; ++i) {
                int idx = tid + i * 256;
                int kr, nc;
                if (BN == 128) { kr = idx >> 5; nc = (idx & 31) << 2; }
                else           { kr = idx >> 4; nc = (idx & 15) << 2; }
                float4 v = *(const float4*)(Bg + (long long)(k0 + kr) * ldb + (n0 + nc));
                float vv[4] = {v.x, v.y, v.z, v.w};
                #pragma unroll
                for (int j = 0; j < 4; ++j) {
                    unsigned p = cvt_hl(vv[j]);
                    Bh[nc + j][kr] = (short)(p & 0xFFFF);
                    Bl[nc + j][kr] = (short)(p >> 16);
                }
            }
        }
        __syncthreads();

        short8 a_h[2], a_l[2];
        a_h[0] = *(const short8*)&Ah[wrow +      l15][lg * 8];
        a_h[1] = *(const short8*)&Ah[wrow + 16 + l15][lg * 8];
        a_l[0] = *(const short8*)&Al[wrow +      l15][lg * 8];
        a_l[1] = *(const short8*)&Al[wrow + 16 + l15][lg * 8];
        #pragma unroll
        for (int nf = 0; nf < NF; ++nf) {
            short8 b_h = *(const short8*)&Bh[wcol + nf * 16 + l15][lg * 8];
            short8 b_l = *(const short8*)&Bl[wcol + nf * 16 + l15][lg * 8];
            #pragma unroll
            for (int mf = 0; mf < 2; ++mf) {
                acc[mf][nf] = __builtin_amdgcn_mfma_f32_16x16x32_bf16(a_h[mf], b_h, acc[mf][nf], 0, 0, 0);
                acc[mf][nf] = __builtin_amdgcn_mfma_f32_16x16x32_bf16(a_h[mf], b_l, acc[mf][nf], 0, 0, 0);
                acc[mf][nf] = __builtin_amdgcn_mfma_f32_16x16x32_bf16(a_l[mf], b_h, acc[mf][nf], 0, 0, 0);
            }
        }
        __syncthreads();
    }

    if (EPI == 0) {
        #pragma unroll
        for (int mf = 0; mf < 2; ++mf)
            #pragma unroll
            for (int nf = 0; nf < NF; ++nf) {
                int row = m0 + wrow + mf * 16 + lg * 4;
                int col = n0 + wcol + nf * 16 + l15;
                #pragma unroll
                for (int j = 0; j < 4; ++j)
                    Cg[(long long)(row + j) * ldc + col] = acc[mf][nf][j] * scale;
            }
    } else {
        float s = 0.0f;
        #pragma unroll
        for (int mf = 0; mf < 2; ++mf)
            #pragma unroll
            for (int nf = 0; nf < NF; ++nf) {
                int row = m0 + wrow + mf * 16 + lg * 4;
                int col = n0 + wcol + nf * 16 + l15;
                #pragma unroll
                for (int j = 0; j < 4; ++j)
                    if (row + j != col) { float c = acc[mf][nf][j]; s += c * c; }
            }
        #pragma unroll
        for (int o = 32; o; o >>= 1) s += __shfl_down(s, o, 64);
        if (lane == 0) red[w] = s;
        __syncthreads();
        if (tid == 0) atomicAdd(lossAcc, red[0] + red[1] + red[2] + red[3]);
    }
}

// ---------------- softmax kernels ----------------
__device__ inline float waveMax(float v) {
    #pragma unroll
    for (int o = 32; o; o >>= 1) v = fmaxf(v, __shfl_xor(v, o, 64));
    return v;
}
__device__ inline float waveSum(float v) {
    #pragma unroll
    for (int o = 32; o; o >>= 1) v += __shfl_xor(v, o, 64);
    return v;
}

// pAlpha[b,r,:] = softmax over l of masked pScoreT[b,r,:]  (coalesced rows of [B,R,L])
__global__ __launch_bounds__(256) void softmax_LT(
    const float* __restrict__ pT, const int* __restrict__ mask, float* __restrict__ pAlpha)
{
    __shared__ float sm[4], ss[4];
    int zi = blockIdx.x;              // b*R + r
    int b = zi >> 8;
    const float* row = pT + (long long)zi * L_;
    const int* mk = mask + (long long)b * L_ * L_;   // row 0 of [L,L]
    float vals[8];
    float mx = -3.4e38f;
    #pragma unroll
    for (int i = 0; i < 8; ++i) {
        int l = threadIdx.x + i * 256;
        float v = row[l];
        if (mk[l] == 0) v = MASK_NEG;
        vals[i] = v; mx = fmaxf(mx, v);
    }
    int lane = threadIdx.x & 63, wid = threadIdx.x >> 6;
    mx = waveMax(mx);
    if (lane == 0) sm[wid] = mx;
    __syncthreads();
    mx = fmaxf(fmaxf(sm[0], sm[1]), fmaxf(sm[2], sm[3]));
    float sum = 0.0f;
    #pragma unroll
    for (int i = 0; i < 8; ++i) { float e = __expf(vals[i] - mx); vals[i] = e; sum += e; }
    sum = waveSum(sum);
    if (lane == 0) ss[wid] = sum;
    __syncthreads();
    sum = ss[0] + ss[1] + ss[2] + ss[3];
    float inv = 1.0f / sum;
    float* out = pAlpha + (long long)zi * L_;
    #pragma unroll
    for (int i = 0; i < 8; ++i) out[threadIdx.x + i * 256] = vals[i] * inv;
}

// pAlpha_[b,l,:] = softmax over r of masked pScore[b,l,:]
__global__ __launch_bounds__(256) void softmax_R(
    const float* __restrict__ pScore, const int* __restrict__ mask, float* __restrict__ pAlpha_)
{
    __shared__ float sm[4], ss[4];
    long long z = blockIdx.x;    // b*L + l
    int b = (int)(z >> 11), l = (int)(z & 2047);
    bool pad = (mask[(long long)b * L_ * L_ + l] == 0);
    float v = pScore[z * R_ + threadIdx.x];
    if (pad) v = MASK_NEG;
    int lane = threadIdx.x & 63, wid = threadIdx.x >> 6;
    float mx = waveMax(v);
    if (lane == 0) sm[wid] = mx;
    __syncthreads();
    mx = fmaxf(fmaxf(sm[0], sm[1]), fmaxf(sm[2], sm[3]));
    float e = __expf(v - mx);
    float sum = waveSum(e);
    if (lane == 0) ss[wid] = sum;
    __syncthreads();
    sum = ss[0] + ss[1] + ss[2] + ss[3];
    pAlpha_[z * R_ + threadIdx.x] = e / sum;
}

// alpha = softmax(scores,-1); per-row offdiag sum -> offArr[row] (no global atomic)
__global__ __launch_bounds__(256) void softmax_alpha(
    const float* __restrict__ scores, float* __restrict__ alpha, float* __restrict__ offArr)
{
    __shared__ float sm[4], ss[4], so[4];
    long long row = blockIdx.x;  // over B*H*R
    int r = (int)(row & 255);
    float v = scores[row * 256 + threadIdx.x];
    int lane = threadIdx.x & 63, wid = threadIdx.x >> 6;
    float mx = waveMax(v);
    if (lane == 0) sm[wid] = mx;
    __syncthreads();
    mx = fmaxf(fmaxf(sm[0], sm[1]), fmaxf(sm[2], sm[3]));
    float e = __expf(v - mx);
    float sum = waveSum(e);
    if (lane == 0) ss[wid] = sum;
    __syncthreads();
    sum = ss[0] + ss[1] + ss[2] + ss[3];
    float a = e / sum;
    alpha[row * 256 + threadIdx.x] = a;
    float off = (threadIdx.x == r) ? 0.0f : a;
    off = waveSum(off);
    if (lane == 0) so[wid] = off;
    __syncthreads();
    if (threadIdx.x == 0) offArr[row] = so[0] + so[1] + so[2] + so[3];
}

__global__ __launch_bounds__(256) void finalize_loss(
    const float* __restrict__ addLossIn, const float* __restrict__ lossAcc,
    const float* __restrict__ offArr, float* __restrict__ out)
{
    __shared__ float red[4];
    float s = 0.0f;
    for (int i = threadIdx.x; i < B_ * H_ * R_; i += 256) s += offArr[i];
    int lane = threadIdx.x & 63, wid = threadIdx.x >> 6;
    s = waveSum(s);
    if (lane == 0) red[wid] = s;
    __syncthreads();
    if (threadIdx.x == 0) {
        float total = red[0] + red[1] + red[2] + red[3];
        out[0] = addLossIn[0]
               + lossAcc[0] * (1.0f / ((float)B_ * R_ * R_))
               + total      * (1.0f / ((float)B_ * H_ * R_ * R_))
               + lossAcc[2] * (1.0f / ((float)B_ * R_ * R_));
    }
}

// ---------------- launch ----------------
extern "C" void kernel_launch(void* const* d_in, const int* in_sizes, int n_in,
                              void* d_out, int out_size, void* d_ws, size_t ws_size,
                              hipStream_t stream)
{
    const float* qx = (const float*)d_in[0];
    const float* kx = (const float*)d_in[1];
    const float* vx = (const float*)d_in[2];
    const float* addLossIn = (const float*)d_in[3];
    const int* mask = (const int*)d_in[4];
    const float* Wp = (const float*)d_in[5];
    const float* WQ = (const float*)d_in[6];
    const float* WK = (const float*)d_in[7];
    const float* WV = (const float*)d_in[8];
    const float* WO = (const float*)d_in[9];

    float* zOut      = (float*)d_out;                             // [B,L,C]
    float* scoresOut = zOut + (long long)B_ * L_ * C_;            // [B,H,R,R]
    float* lossOut   = scoresOut + (long long)B_ * H_ * R_ * R_;  // [1]

    float* w = (float*)d_ws;
    const long long SZ_BLR = (long long)B_ * L_ * R_;   // 4M
    const long long SZ_BRC = (long long)B_ * R_ * C_;   // 1M
    float* pScore  = w;                    // [B,L,R]
    float* pScoreT = w + SZ_BLR;           // [B,R,L]
    float* pAlpha  = w + 2 * SZ_BLR;       // [B,R,L]
    float* pAlpha_ = w + 3 * SZ_BLR;       // [B,L,R]
    float* qr = w + 4 * SZ_BLR;
    float* kr = qr + SZ_BRC;
    float* vr = kr + SZ_BRC;
    float* qp = vr + SZ_BRC;
    float* kp = qp + SZ_BRC;
    float* vp = kp + SZ_BRC;
    float* z1 = vp + SZ_BRC;
    float* loss   = z1 + SZ_BRC;           // 3 floats
    float* offArr = loss + 16;             // 16384 floats
    float* alpha = pScore;                 // reuse (pScore dead after softmax_R)
    float* z2 = qr;                        // reuse (qr dead after projections)

    const float* np = nullptr;
    float* npo = nullptr;

    (void)hipMemsetAsync(loss, 0, 3 * sizeof(float), stream);

    // 1) pScore = vx @ Wp^T : [16384, 256], K=512
    gemm_mx<128, false, false, 0, false><<<dim3(2, 256, 1), 256, 0, stream>>>(
        vx, np, np, Wp, np, np, pScore, npo, npo,
        C_, C_, C_, R_, 1, 0, 0, 0, 0, 0, 0, 1.0f, nullptr);

    // 2) pScoreT[b] = Wp @ vx[b]^T : [256, 2048] per batch, K=512
    gemm_mx<128, false, false, 0, false><<<dim3(16, 4, 8), 256, 0, stream>>>(
        Wp, np, np, vx, np, np, pScoreT, npo, npo,
        C_, C_, C_, L_, 8, 0, 0, 0, (long long)L_ * C_, 0, (long long)R_ * L_, 1.0f, nullptr);

    // 3) softmaxes
    softmax_LT<<<B_ * R_, 256, 0, stream>>>(pScoreT, mask, pAlpha);
    softmax_R<<<B_ * L_, 256, 0, stream>>>(pScore, mask, pAlpha_);

    // 4) loss1: sum offdiag (pAlpha @ pAlpha^T)^2, K=2048
    gemm_mx<128, false, false, 1, false><<<dim3(2, 4, 8), 256, 0, stream>>>(
        pAlpha, np, np, pAlpha, np, np, npo, npo, npo,
        L_, L_, L_, 0, 8, 0, (long long)R_ * L_, 0, (long long)R_ * L_, 0, 0, 1.0f, loss + 0);

    // 5) loss3: sum offdiag (pAlpha_^T @ pAlpha_)^2, K=2048
    gemm_mx<128, true, true, 1, false><<<dim3(2, 4, 8), 256, 0, stream>>>(
        pAlpha_, np, np, pAlpha_, np, np, npo, npo, npo,
        L_, R_, R_, 0, 8, 0, (long long)L_ * R_, 0, (long long)L_ * R_, 0, 0, 1.0f, loss + 2);

    // 6) qr/kr/vr = pAlpha @ {qx,kx,vx} : [256,512] per batch, K=2048 (fused triple)
    gemm_mx<128, false, true, 0, true><<<dim3(4, 4, 24), 256, 0, stream>>>(
        pAlpha, pAlpha, pAlpha, qx, kx, vx, qr, kr, vr,
        L_, L_, C_, C_, 8,
        0, (long long)R_ * L_, 0, (long long)L_ * C_, 0, (long long)R_ * C_, 1.0f, nullptr);

    // 7) projections: {qp,kp,vp} = {qr,kr,vr} @ {WQ,WK,WV}^T : [2048,512], K=512 (fused triple)
    gemm_mx<128, false, false, 0, true><<<dim3(4, 32, 3), 256, 0, stream>>>(
        qr, kr, vr, WQ, WK, WV, qp, kp, vp,
        C_, C_, C_, HD_, 1, 0, 0, 0, 0, 0, 0, 1.0f, nullptr);

    // 8) scores[b,h] = qp[b,:,h*64:] @ kp[b,:,h*64:]^T / 8 : [256,256], K=64
    gemm_mx<128, false, false, 0, false><<<dim3(2, 4, 64), 256, 0, stream>>>(
        qp, np, np, kp, np, np, scoresOut, npo, npo,
        DK_, HD_, HD_, R_, 8,
        (long long)R_ * HD_, 64, (long long)R_ * HD_, 64,
        (long long)H_ * R_ * R_, (long long)R_ * R_, 0.125f, nullptr);

    // 9) alpha = softmax(scores) + per-row offdiag sums
    softmax_alpha<<<B_ * H_ * R_, 256, 0, stream>>>(scoresOut, alpha, offArr);

    // 10) z1[b,:,h*64:] = alpha[b,h] @ vp[b,:,h*64:] : [256,64], K=256
    gemm_mx<64, false, true, 0, false><<<dim3(1, 4, 64), 256, 0, stream>>>(
        alpha, np, np, vp, np, np, z1, npo, npo,
        R_, R_, HD_, HD_, 8,
        (long long)H_ * R_ * R_, (long long)R_ * R_, (long long)R_ * HD_, 64,
        (long long)R_ * HD_, 64, 1.0f, nullptr);

    // 11) z2 = z1 @ WO^T : [2048,512], K=512
    gemm_mx<128, false, false, 0, false><<<dim3(4, 32, 1), 256, 0, stream>>>(
        z1, np, np, WO, np, np, z2, npo, npo,
        HD_, HD_, HD_, C_, 1, 0, 0, 0, 0, 0, 0, 1.0f, nullptr);

    // 12) z = pAlpha_ @ z2 : [2048,512] per batch, K=256
    gemm_mx<128, false, true, 0, false><<<dim3(4, 32, 8), 256, 0, stream>>>(
        pAlpha_, np, np, z2, np, np, zOut, npo, npo,
        R_, R_, C_, C_, 8,
        0, (long long)L_ * R_, 0, (long long)R_ * C_, 0, (long long)L_ * C_, 1.0f, nullptr);

    // 13) addLoss
    finalize_loss<<<1, 256, 0, stream>>>(addLossIn, loss, offArr, lossOut);
}

// Round 5
// 467.690 us; speedup vs baseline: 2.8461x; 2.1320x over previous
//
#include <hip/hip_runtime.h>

#define B_  8
#define L_  2048
#define C_  512
#define R_  256
#define H_  8
#define DK_ 64
#define HD_ 512
#define MASK_NEG (-32767.0f)

typedef __attribute__((ext_vector_type(8))) short short8;
typedef __attribute__((ext_vector_type(8))) unsigned short ushort8;
typedef __attribute__((ext_vector_type(4))) unsigned short ushort4_t;
typedef __attribute__((ext_vector_type(4))) float f32x4;
typedef unsigned short u16;

__device__ inline u16 bf16_rne(float x) {
    unsigned u = __float_as_uint(x);
    return (u16)((u + 0x7FFFu + ((u >> 16) & 1u)) >> 16);
}
// hi bf16 in low 16 bits, lo bf16 in high 16 bits
__device__ inline unsigned cvt_hl(float x) {
    u16 hh = bf16_rne(x);
    float hf = __uint_as_float(((unsigned)hh) << 16);
    u16 ll = bf16_rne(x - hf);
    return (unsigned)hh | ((unsigned)ll << 16);
}

struct Ptr3 { const void* p0; const void* p1; const void* p2; };

// ---------------- MFMA plane GEMM ----------------
// C = scale * A @ B via 3-term split MFMA (Ah@Bh + Ah@Bl + Al@Bh).
// AMODE: 0 = bf16 planes [M][K]; 1 = bf16 planes [K][M] (gather); 2 = fp32 [M][K] (cvt)
// BMODE: 0 = bf16 planes [N][K]; 1 = bf16 planes [K][N] (gather);
//        2 = fp32 [N][K] (cvt);  3 = fp32 [K][N] (gather+cvt)
// EPI:   0 = store fp32 C*scale; 1 = atomicAdd sum offdiag(C)^2; 2 = store hi/lo planes
// Batch: z -> zb=z/divz, zh=z%divz. TRIPLE: zb picks pointer from Ptr3, else *sb strides.
template<int BN, int AMODE, int BMODE, int EPI, bool TRIPLE>
__global__ __launch_bounds__(256) void gemm_pl(
    Ptr3 aH, Ptr3 aL, Ptr3 bH, Ptr3 bL, Ptr3 cH, Ptr3 cL,
    int K, int lda, int ldb, int ldc, int divz,
    long long ash, long long bsh, long long csh,
    long long asb, long long bsb, long long csb,
    float scale, float* __restrict__ lossAcc)
{
    constexpr int NF = BN / 32;
    __shared__ u16 Ahs[64][40], Als[64][40];
    __shared__ u16 Bhs[BN][40], Bls[BN][40];
    __shared__ float red[4];

    const int z  = blockIdx.z;
    const int zb = z / divz, zh = z - zb * divz;
    const void* avH = TRIPLE ? (zb == 0 ? aH.p0 : zb == 1 ? aH.p1 : aH.p2) : aH.p0;
    const void* avL = TRIPLE ? (zb == 0 ? aL.p0 : zb == 1 ? aL.p1 : aL.p2) : aL.p0;
    const void* bvH = TRIPLE ? (zb == 0 ? bH.p0 : zb == 1 ? bH.p1 : bH.p2) : bH.p0;
    const void* bvL = TRIPLE ? (zb == 0 ? bL.p0 : zb == 1 ? bL.p1 : bL.p2) : bL.p0;
    void* cvH = (void*)(TRIPLE ? (zb == 0 ? cH.p0 : zb == 1 ? cH.p1 : cH.p2) : cH.p0);
    void* cvL = (void*)(TRIPLE ? (zb == 0 ? cL.p0 : zb == 1 ? cL.p1 : cL.p2) : cL.p0);
    const long long ao = (TRIPLE ? 0 : (long long)zb * asb) + (long long)zh * ash;
    const long long bo = (TRIPLE ? 0 : (long long)zb * bsb) + (long long)zh * bsh;
    const long long co = (TRIPLE ? 0 : (long long)zb * csb) + (long long)zh * csh;

    const u16*   AHg = (const u16*)avH + ao;
    const u16*   ALg = (const u16*)avL + ao;
    const float* Afg = (const float*)avH + ao;
    const u16*   BHg = (const u16*)bvH + bo;
    const u16*   BLg = (const u16*)bvL + bo;
    const float* Bfg = (const float*)bvH + bo;
    float* Cf  = (float*)cvH + co;
    u16*   CHg = (u16*)cvH + co;
    u16*   CLg = (u16*)cvL + co;

    const int m0 = blockIdx.y * 64, n0 = blockIdx.x * BN;
    const int tid = threadIdx.x;
    const int lane = tid & 63, w = tid >> 6;
    const int wrow = (w >> 1) * 32, wcol = (w & 1) * (BN / 2);
    const int l15 = lane & 15, lg = lane >> 4;

    f32x4 zero = {0.f, 0.f, 0.f, 0.f};
    f32x4 acc[2][NF];
    #pragma unroll
    for (int mf = 0; mf < 2; ++mf)
        #pragma unroll
        for (int nf = 0; nf < NF; ++nf) acc[mf][nf] = zero;

    for (int k0 = 0; k0 < K; k0 += 32) {
        // ---- stage A (64 x 32) ----
        if (AMODE == 0) {
            int row = tid >> 2, kc = (tid & 3) << 3;
            long long off = (long long)(m0 + row) * lda + (k0 + kc);
            *(ushort8*)&Ahs[row][kc] = *(const ushort8*)(AHg + off);
            *(ushort8*)&Als[row][kc] = *(const ushort8*)(ALg + off);
        } else if (AMODE == 2) {
            int row = tid >> 2, kc = (tid & 3) << 3;
            const float* s = Afg + (long long)(m0 + row) * lda + (k0 + kc);
            float4 v0 = *(const float4*)s, v1 = *(const float4*)(s + 4);
            unsigned p0 = cvt_hl(v0.x), p1 = cvt_hl(v0.y), p2 = cvt_hl(v0.z), p3 = cvt_hl(v0.w);
            unsigned p4 = cvt_hl(v1.x), p5 = cvt_hl(v1.y), p6 = cvt_hl(v1.z), p7 = cvt_hl(v1.w);
            ushort8 h, l;
            h[0]=(u16)p0; h[1]=(u16)p1; h[2]=(u16)p2; h[3]=(u16)p3;
            h[4]=(u16)p4; h[5]=(u16)p5; h[6]=(u16)p6; h[7]=(u16)p7;
            l[0]=(u16)(p0>>16); l[1]=(u16)(p1>>16); l[2]=(u16)(p2>>16); l[3]=(u16)(p3>>16);
            l[4]=(u16)(p4>>16); l[5]=(u16)(p5>>16); l[6]=(u16)(p6>>16); l[7]=(u16)(p7>>16);
            *(ushort8*)&Ahs[row][kc] = h;
            *(ushort8*)&Als[row][kc] = l;
        } else { // AMODE == 1: planes [K][M], gather 4 k per column
            #pragma unroll
            for (int t = tid; t < 512; t += 256) {
                int col = t & 63, kg = t >> 6;
                ushort4_t h, l;
                #pragma unroll
                for (int j = 0; j < 4; ++j) {
                    long long off = (long long)(k0 + kg * 4 + j) * lda + (m0 + col);
                    h[j] = AHg[off]; l[j] = ALg[off];
                }
                *(ushort4_t*)&Ahs[col][kg * 4] = h;
                *(ushort4_t*)&Als[col][kg * 4] = l;
            }
        }
        // ---- stage B (BN x 32) ----
        if (BMODE == 0) {
            #pragma unroll
            for (int t = tid; t < BN * 4; t += 256) {
                int row = t >> 2, kc = (t & 3) << 3;
                long long off = (long long)(n0 + row) * ldb + (k0 + kc);
                *(ushort8*)&Bhs[row][kc] = *(const ushort8*)(BHg + off);
                *(ushort8*)&Bls[row][kc] = *(const ushort8*)(BLg + off);
            }
        } else if (BMODE == 2) {
            #pragma unroll
            for (int t = tid; t < BN * 4; t += 256) {
                int row = t >> 2, kc = (t & 3) << 3;
                const float* s = Bfg + (long long)(n0 + row) * ldb + (k0 + kc);
                float4 v0 = *(const float4*)s, v1 = *(const float4*)(s + 4);
                unsigned p0 = cvt_hl(v0.x), p1 = cvt_hl(v0.y), p2 = cvt_hl(v0.z), p3 = cvt_hl(v0.w);
                unsigned p4 = cvt_hl(v1.x), p5 = cvt_hl(v1.y), p6 = cvt_hl(v1.z), p7 = cvt_hl(v1.w);
                ushort8 h, l;
                h[0]=(u16)p0; h[1]=(u16)p1; h[2]=(u16)p2; h[3]=(u16)p3;
                h[4]=(u16)p4; h[5]=(u16)p5; h[6]=(u16)p6; h[7]=(u16)p7;
                l[0]=(u16)(p0>>16); l[1]=(u16)(p1>>16); l[2]=(u16)(p2>>16); l[3]=(u16)(p3>>16);
                l[4]=(u16)(p4>>16); l[5]=(u16)(p5>>16); l[6]=(u16)(p6>>16); l[7]=(u16)(p7>>16);
                *(ushort8*)&Bhs[row][kc] = h;
                *(ushort8*)&Bls[row][kc] = l;
            }
        } else if (BMODE == 1) { // planes [K][N], gather
            #pragma unroll
            for (int t = tid; t < BN * 8; t += 256) {
                int col = t % BN, kg = t / BN;
                ushort4_t h, l;
                #pragma unroll
                for (int j = 0; j < 4; ++j) {
                    long long off = (long long)(k0 + kg * 4 + j) * ldb + (n0 + col);
                    h[j] = BHg[off]; l[j] = BLg[off];
                }
                *(ushort4_t*)&Bhs[col][kg * 4] = h;
                *(ushort4_t*)&Bls[col][kg * 4] = l;
            }
        } else { // BMODE == 3: fp32 [K][N], gather + cvt
            #pragma unroll
            for (int t = tid; t < BN * 8; t += 256) {
                int col = t % BN, kg = t / BN;
                ushort4_t h, l;
                #pragma unroll
                for (int j = 0; j < 4; ++j) {
                    long long off = (long long)(k0 + kg * 4 + j) * ldb + (n0 + col);
                    unsigned p = cvt_hl(Bfg[off]);
                    h[j] = (u16)p; l[j] = (u16)(p >> 16);
                }
                *(ushort4_t*)&Bhs[col][kg * 4] = h;
                *(ushort4_t*)&Bls[col][kg * 4] = l;
            }
        }
        __syncthreads();

        short8 a_h[2], a_l[2];
        a_h[0] = *(const short8*)&Ahs[wrow +      l15][lg * 8];
        a_h[1] = *(const short8*)&Ahs[wrow + 16 + l15][lg * 8];
        a_l[0] = *(const short8*)&Als[wrow +      l15][lg * 8];
        a_l[1] = *(const short8*)&Als[wrow + 16 + l15][lg * 8];
        #pragma unroll
        for (int nf = 0; nf < NF; ++nf) {
            short8 b_h = *(const short8*)&Bhs[wcol + nf * 16 + l15][lg * 8];
            short8 b_l = *(const short8*)&Bls[wcol + nf * 16 + l15][lg * 8];
            #pragma unroll
            for (int mf = 0; mf < 2; ++mf) {
                acc[mf][nf] = __builtin_amdgcn_mfma_f32_16x16x32_bf16(a_h[mf], b_h, acc[mf][nf], 0, 0, 0);
                acc[mf][nf] = __builtin_amdgcn_mfma_f32_16x16x32_bf16(a_h[mf], b_l, acc[mf][nf], 0, 0, 0);
                acc[mf][nf] = __builtin_amdgcn_mfma_f32_16x16x32_bf16(a_l[mf], b_h, acc[mf][nf], 0, 0, 0);
            }
        }
        __syncthreads();
    }

    if (EPI == 0) {
        #pragma unroll
        for (int mf = 0; mf < 2; ++mf)
            #pragma unroll
            for (int nf = 0; nf < NF; ++nf) {
                int row = m0 + wrow + mf * 16 + lg * 4;
                int col = n0 + wcol + nf * 16 + l15;
                #pragma unroll
                for (int j = 0; j < 4; ++j)
                    Cf[(long long)(row + j) * ldc + col] = acc[mf][nf][j] * scale;
            }
    } else if (EPI == 2) {
        #pragma unroll
        for (int mf = 0; mf < 2; ++mf)
            #pragma unroll
            for (int nf = 0; nf < NF; ++nf) {
                int row = m0 + wrow + mf * 16 + lg * 4;
                int col = n0 + wcol + nf * 16 + l15;
                #pragma unroll
                for (int j = 0; j < 4; ++j) {
                    unsigned p = cvt_hl(acc[mf][nf][j] * scale);
                    CHg[(long long)(row + j) * ldc + col] = (u16)p;
                    CLg[(long long)(row + j) * ldc + col] = (u16)(p >> 16);
                }
            }
    } else {
        float s = 0.0f;
        #pragma unroll
        for (int mf = 0; mf < 2; ++mf)
            #pragma unroll
            for (int nf = 0; nf < NF; ++nf) {
                int row = m0 + wrow + mf * 16 + lg * 4;
                int col = n0 + wcol + nf * 16 + l15;
                #pragma unroll
                for (int j = 0; j < 4; ++j)
                    if (row + j != col) { float c = acc[mf][nf][j]; s += c * c; }
            }
        #pragma unroll
        for (int o = 32; o; o >>= 1) s += __shfl_down(s, o, 64);
        if (lane == 0) red[w] = s;
        __syncthreads();
        if (tid == 0) atomicAdd(lossAcc, red[0] + red[1] + red[2] + red[3]);
    }
}

// ---------------- helpers ----------------
__device__ inline float waveMax(float v) {
    #pragma unroll
    for (int o = 32; o; o >>= 1) v = fmaxf(v, __shfl_xor(v, o, 64));
    return v;
}
__device__ inline float waveSum(float v) {
    #pragma unroll
    for (int o = 32; o; o >>= 1) v += __shfl_xor(v, o, 64);
    return v;
}

// fp32 -> hi/lo bf16 planes (for weights)
__global__ __launch_bounds__(256) void conv_planes(
    const float* __restrict__ src, u16* __restrict__ h, u16* __restrict__ l, int n4)
{
    int i = blockIdx.x * 256 + threadIdx.x;
    if (i >= n4) return;
    float4 v = ((const float4*)src)[i];
    unsigned p0 = cvt_hl(v.x), p1 = cvt_hl(v.y), p2 = cvt_hl(v.z), p3 = cvt_hl(v.w);
    ushort4_t hv, lv;
    hv[0]=(u16)p0; hv[1]=(u16)p1; hv[2]=(u16)p2; hv[3]=(u16)p3;
    lv[0]=(u16)(p0>>16); lv[1]=(u16)(p1>>16); lv[2]=(u16)(p2>>16); lv[3]=(u16)(p3>>16);
    ((ushort4_t*)h)[i] = hv;
    ((ushort4_t*)l)[i] = lv;
}

// pAlpha[b,r,:] = softmax over l of masked pScoreT[b,r,:] -> hi/lo planes
__global__ __launch_bounds__(256) void softmax_LT(
    const float* __restrict__ pT, const int* __restrict__ mask,
    u16* __restrict__ outH, u16* __restrict__ outL)
{
    __shared__ float sm[4], ss[4];
    int zi = blockIdx.x;              // b*R + r
    int b = zi >> 8;
    const float* row = pT + (long long)zi * L_;
    const int* mk = mask + (long long)b * L_ * L_;   // row 0 of [L,L]
    float vals[8];
    float mx = -3.4e38f;
    #pragma unroll
    for (int i = 0; i < 8; ++i) {
        int l = threadIdx.x + i * 256;
        float v = row[l];
        if (mk[l] == 0) v = MASK_NEG;
        vals[i] = v; mx = fmaxf(mx, v);
    }
    int lane = threadIdx.x & 63, wid = threadIdx.x >> 6;
    mx = waveMax(mx);
    if (lane == 0) sm[wid] = mx;
    __syncthreads();
    mx = fmaxf(fmaxf(sm[0], sm[1]), fmaxf(sm[2], sm[3]));
    float sum = 0.0f;
    #pragma unroll
    for (int i = 0; i < 8; ++i) { float e = __expf(vals[i] - mx); vals[i] = e; sum += e; }
    sum = waveSum(sum);
    if (lane == 0) ss[wid] = sum;
    __syncthreads();
    sum = ss[0] + ss[1] + ss[2] + ss[3];
    float inv = 1.0f / sum;
    long long base = (long long)zi * L_;
    #pragma unroll
    for (int i = 0; i < 8; ++i) {
        unsigned p = cvt_hl(vals[i] * inv);
        outH[base + threadIdx.x + i * 256] = (u16)p;
        outL[base + threadIdx.x + i * 256] = (u16)(p >> 16);
    }
}

// pAlpha_[b,l,:] = softmax over r of masked pScore[b,l,:] -> hi/lo planes
__global__ __launch_bounds__(256) void softmax_R(
    const float* __restrict__ pScore, const int* __restrict__ mask,
    u16* __restrict__ outH, u16* __restrict__ outL)
{
    __shared__ float sm[4], ss[4];
    long long z = blockIdx.x;    // b*L + l
    int b = (int)(z >> 11), l = (int)(z & 2047);
    bool pad = (mask[(long long)b * L_ * L_ + l] == 0);
    float v = pScore[z * R_ + threadIdx.x];
    if (pad) v = MASK_NEG;
    int lane = threadIdx.x & 63, wid = threadIdx.x >> 6;
    float mx = waveMax(v);
    if (lane == 0) sm[wid] = mx;
    __syncthreads();
    mx = fmaxf(fmaxf(sm[0], sm[1]), fmaxf(sm[2], sm[3]));
    float e = __expf(v - mx);
    float sum = waveSum(e);
    if (lane == 0) ss[wid] = sum;
    __syncthreads();
    sum = ss[0] + ss[1] + ss[2] + ss[3];
    unsigned p = cvt_hl(e / sum);
    outH[z * R_ + threadIdx.x] = (u16)p;
    outL[z * R_ + threadIdx.x] = (u16)(p >> 16);
}

// alpha = softmax(scores,-1) -> planes; per-row offdiag sum -> offArr[row]
__global__ __launch_bounds__(256) void softmax_alpha(
    const float* __restrict__ scores, u16* __restrict__ aH, u16* __restrict__ aL,
    float* __restrict__ offArr)
{
    __shared__ float sm[4], ss[4], so[4];
    long long row = blockIdx.x;  // over B*H*R
    int r = (int)(row & 255);
    float v = scores[row * 256 + threadIdx.x];
    int lane = threadIdx.x & 63, wid = threadIdx.x >> 6;
    float mx = waveMax(v);
    if (lane == 0) sm[wid] = mx;
    __syncthreads();
    mx = fmaxf(fmaxf(sm[0], sm[1]), fmaxf(sm[2], sm[3]));
    float e = __expf(v - mx);
    float sum = waveSum(e);
    if (lane == 0) ss[wid] = sum;
    __syncthreads();
    sum = ss[0] + ss[1] + ss[2] + ss[3];
    float a = e / sum;
    unsigned p = cvt_hl(a);
    aH[row * 256 + threadIdx.x] = (u16)p;
    aL[row * 256 + threadIdx.x] = (u16)(p >> 16);
    float off = (threadIdx.x == r) ? 0.0f : a;
    off = waveSum(off);
    if (lane == 0) so[wid] = off;
    __syncthreads();
    if (threadIdx.x == 0) offArr[row] = so[0] + so[1] + so[2] + so[3];
}

__global__ __launch_bounds__(256) void finalize_loss(
    const float* __restrict__ addLossIn, const float* __restrict__ lossAcc,
    const float* __restrict__ offArr, float* __restrict__ out)
{
    __shared__ float red[4];
    float s = 0.0f;
    for (int i = threadIdx.x; i < B_ * H_ * R_; i += 256) s += offArr[i];
    int lane = threadIdx.x & 63, wid = threadIdx.x >> 6;
    s = waveSum(s);
    if (lane == 0) red[wid] = s;
    __syncthreads();
    if (threadIdx.x == 0) {
        float total = red[0] + red[1] + red[2] + red[3];
        out[0] = addLossIn[0]
               + lossAcc[0] * (1.0f / ((float)B_ * R_ * R_))
               + total      * (1.0f / ((float)B_ * H_ * R_ * R_))
               + lossAcc[2] * (1.0f / ((float)B_ * R_ * R_));
    }
}

// ---------------- launch ----------------
extern "C" void kernel_launch(void* const* d_in, const int* in_sizes, int n_in,
                              void* d_out, int out_size, void* d_ws, size_t ws_size,
                              hipStream_t stream)
{
    const float* qx = (const float*)d_in[0];
    const float* kx = (const float*)d_in[1];
    const float* vx = (const float*)d_in[2];
    const float* addLossIn = (const float*)d_in[3];
    const int* mask = (const int*)d_in[4];
    const float* Wp = (const float*)d_in[5];
    const float* WQ = (const float*)d_in[6];
    const float* WK = (const float*)d_in[7];
    const float* WV = (const float*)d_in[8];
    const float* WO = (const float*)d_in[9];

    float* zOut      = (float*)d_out;                             // [B,L,C]
    float* scoresOut = zOut + (long long)B_ * L_ * C_;            // [B,H,R,R]
    float* lossOut   = scoresOut + (long long)B_ * H_ * R_ * R_;  // [1]

    const long long SZ_BLR = (long long)B_ * L_ * R_;   // 4.19M elems
    const long long SZ_BRC = (long long)B_ * R_ * C_;   // 1.05M elems
    float* w = (float*)d_ws;

    float* pScore  = w;                          // fp32 [B,L,R]
    float* pScoreT = w + SZ_BLR;                 // fp32 [B,R,L]
    u16* pAlphaH   = (u16*)(w + 2 * SZ_BLR);     // [B,R,L] planes
    u16* pAlphaL   = pAlphaH + SZ_BLR;
    u16* pAlpha_H  = pAlphaH + 2 * SZ_BLR;       // [B,L,R] planes
    u16* pAlpha_L  = pAlphaH + 3 * SZ_BLR;
    u16* qrH = pAlphaH + 4 * SZ_BLR;             // 12 planes of SZ_BRC
    u16* qrL = qrH + SZ_BRC;
    u16* krH = qrH + 2 * SZ_BRC;
    u16* krL = qrH + 3 * SZ_BRC;
    u16* vrH = qrH + 4 * SZ_BRC;
    u16* vrL = qrH + 5 * SZ_BRC;
    u16* qpH = qrH + 6 * SZ_BRC;
    u16* qpL = qrH + 7 * SZ_BRC;
    u16* kpH = qrH + 8 * SZ_BRC;
    u16* kpL = qrH + 9 * SZ_BRC;
    u16* vpH = qrH + 10 * SZ_BRC;
    u16* vpL = qrH + 11 * SZ_BRC;
    float* wtail = (float*)(qrH + 12 * SZ_BRC);  // = w + 4*SZ_BLR + 6*SZ_BRC floats
    u16* WpH = (u16*)wtail;                      // 131072 each
    u16* WpL = WpH + (long long)R_ * C_;
    u16* WQH = WpL + (long long)R_ * C_;         // 262144 each
    u16* WQL = WQH + (long long)HD_ * C_;
    u16* WKH = WQL + (long long)HD_ * C_;
    u16* WKL = WKH + (long long)HD_ * C_;
    u16* WVH = WKL + (long long)HD_ * C_;
    u16* WVL = WVH + (long long)HD_ * C_;
    u16* WOH = WVL + (long long)HD_ * C_;
    u16* WOL = WOH + (long long)HD_ * C_;
    float* loss   = (float*)(WOL + (long long)HD_ * C_);
    float* offArr = loss + 16;                   // 16384 floats
    // overlays on dead regions:
    u16* alphaH = (u16*)pScore;                  // [B,H,R,R] planes (pScore dead after softmax_R)
    u16* alphaL = alphaH + (long long)B_ * H_ * R_ * R_;
    u16* z1H = (u16*)pScoreT;                    // planes (pScoreT dead after softmax_LT)
    u16* z1L = z1H + SZ_BRC;
    u16* z2H = z1H + 2 * SZ_BRC;
    u16* z2L = z1H + 3 * SZ_BRC;

    const Ptr3 N3{nullptr, nullptr, nullptr};
    auto P1 = [](const void* p) { return Ptr3{p, p, p}; };
    const long long llRL = (long long)R_ * L_, llLC = (long long)L_ * C_;
    const long long llRC = (long long)R_ * C_, llRHD = (long long)R_ * HD_;
    const long long llRR = (long long)R_ * R_, llHRR = (long long)H_ * R_ * R_;

    (void)hipMemsetAsync(loss, 0, 3 * sizeof(float), stream);

    // 0) weights -> planes
    conv_planes<<<(R_*C_/4 + 255)/256, 256, 0, stream>>>(Wp, WpH, WpL, R_*C_/4);
    conv_planes<<<(HD_*C_/4 + 255)/256, 256, 0, stream>>>(WQ, WQH, WQL, HD_*C_/4);
    conv_planes<<<(HD_*C_/4 + 255)/256, 256, 0, stream>>>(WK, WKH, WKL, HD_*C_/4);
    conv_planes<<<(HD_*C_/4 + 255)/256, 256, 0, stream>>>(WV, WVH, WVL, HD_*C_/4);
    conv_planes<<<(HD_*C_/4 + 255)/256, 256, 0, stream>>>(WO, WOH, WOL, HD_*C_/4);

    // 1) pScore = vx @ Wp^T : [16384,256], K=512
    gemm_pl<128, 2, 0, 0, false><<<dim3(2, 256, 1), 256, 0, stream>>>(
        P1(vx), N3, P1(WpH), P1(WpL), P1(pScore), N3,
        C_, C_, C_, R_, 1, 0, 0, 0, 0, 0, 0, 1.0f, nullptr);

    // 2) pScoreT[b] = Wp @ vx[b]^T : [256,2048] x8, K=512
    gemm_pl<128, 0, 2, 0, false><<<dim3(16, 4, 8), 256, 0, stream>>>(
        P1(WpH), P1(WpL), P1(vx), N3, P1(pScoreT), N3,
        C_, C_, C_, L_, 8, 0, llLC, llRL, 0, 0, 0, 1.0f, nullptr);

    // 3) softmaxes -> planes
    softmax_LT<<<B_ * R_, 256, 0, stream>>>(pScoreT, mask, pAlphaH, pAlphaL);
    softmax_R<<<B_ * L_, 256, 0, stream>>>(pScore, mask, pAlpha_H, pAlpha_L);

    // 4) loss1: offdiag (pAlpha @ pAlpha^T)^2, K=2048
    gemm_pl<64, 0, 0, 1, false><<<dim3(4, 4, 8), 256, 0, stream>>>(
        P1(pAlphaH), P1(pAlphaL), P1(pAlphaH), P1(pAlphaL), N3, N3,
        L_, L_, L_, 0, 8, llRL, llRL, 0, 0, 0, 0, 1.0f, loss + 0);

    // 5) loss3: offdiag (pAlpha_^T @ pAlpha_)^2, K=2048 (gather both)
    gemm_pl<64, 1, 1, 1, false><<<dim3(4, 4, 8), 256, 0, stream>>>(
        P1(pAlpha_H), P1(pAlpha_L), P1(pAlpha_H), P1(pAlpha_L), N3, N3,
        L_, R_, R_, 0, 8, llLC / C_ * R_, (long long)L_ * R_, 0, 0, 0, 0, 1.0f, loss + 2);

    // 6) qr/kr/vr = pAlpha @ {qx,kx,vx} : [256,512] x8, K=2048 (triple, B fp32 gather)
    gemm_pl<64, 0, 3, 2, true><<<dim3(8, 4, 24), 256, 0, stream>>>(
        P1(pAlphaH), P1(pAlphaL), Ptr3{qx, kx, vx}, N3,
        Ptr3{qrH, krH, vrH}, Ptr3{qrL, krL, vrL},
        L_, L_, C_, C_, 8, llRL, llLC, llRC, 0, 0, 0, 1.0f, nullptr);

    // 7) projections: {qp,kp,vp} = {qr,kr,vr} @ {WQ,WK,WV}^T : [2048,512], K=512 (triple)
    gemm_pl<64, 0, 0, 2, true><<<dim3(8, 32, 3), 256, 0, stream>>>(
        Ptr3{qrH, krH, vrH}, Ptr3{qrL, krL, vrL},
        Ptr3{WQH, WKH, WVH}, Ptr3{WQL, WKL, WVL},
        Ptr3{qpH, kpH, vpH}, Ptr3{qpL, kpL, vpL},
        C_, C_, C_, HD_, 1, 0, 0, 0, 0, 0, 0, 1.0f, nullptr);

    // 8) scores = qp_h @ kp_h^T / 8 : [256,256] x64, K=64
    gemm_pl<64, 0, 0, 0, false><<<dim3(4, 4, 64), 256, 0, stream>>>(
        P1(qpH), P1(qpL), P1(kpH), P1(kpL), P1(scoresOut), N3,
        DK_, HD_, HD_, R_, 8, 64, 64, llRR, llRHD, llRHD, llHRR, 0.125f, nullptr);

    // 9) alpha = softmax(scores) -> planes + offArr
    softmax_alpha<<<B_ * H_ * R_, 256, 0, stream>>>(scoresOut, alphaH, alphaL, offArr);

    // 10) z1 = alpha @ vp_h : [256,64] x64, K=256 (B gather)
    gemm_pl<64, 0, 1, 2, false><<<dim3(1, 4, 64), 256, 0, stream>>>(
        P1(alphaH), P1(alphaL), P1(vpH), P1(vpL), P1(z1H), P1(z1L),
        R_, R_, HD_, HD_, 8, llRR, 64, 64, llHRR, llRHD, llRHD, 1.0f, nullptr);

    // 11) z2 = z1 @ WO^T : [2048,512], K=512
    gemm_pl<64, 0, 0, 2, false><<<dim3(8, 32, 1), 256, 0, stream>>>(
        P1(z1H), P1(z1L), P1(WOH), P1(WOL), P1(z2H), P1(z2L),
        HD_, HD_, HD_, C_, 1, 0, 0, 0, 0, 0, 0, 1.0f, nullptr);

    // 12) z = pAlpha_ @ z2 : [2048,512] x8, K=256 (B gather)
    gemm_pl<64, 0, 1, 0, false><<<dim3(8, 32, 8), 256, 0, stream>>>(
        P1(pAlpha_H), P1(pAlpha_L), P1(z2H), P1(z2L), P1(zOut), N3,
        R_, R_, C_, C_, 8, (long long)L_ * R_, llRC, llLC, 0, 0, 0, 1.0f, nullptr);

    // 13) addLoss
    finalize_loss<<<1, 256, 0, stream>>>(addLossIn, loss, offArr, lossOut);
}